// Round 17
// baseline (2769.921 us; speedup 1.0000x reference)
//
#include <hip/hip_runtime.h>

#define T_SEQ 512
#define BATCH 64
#define IN_F  1024
#define HID_F 1024
#define G4    4096

typedef __bf16 bf16x8 __attribute__((ext_vector_type(8)));
typedef float  f32x4  __attribute__((ext_vector_type(4)));
typedef unsigned short u16;
typedef unsigned int   u32;
typedef unsigned long long u64;

__device__ __forceinline__ u16 f2bf(float x) {
    u32 u = __builtin_bit_cast(u32, x);
    u = (u + 0x7FFFu + ((u >> 16) & 1u)) >> 16;   // RTNE
    return (u16)u;
}
__device__ __forceinline__ float bf2f(u16 v) {
    return __builtin_bit_cast(float, (u32)v << 16);
}

__device__ __forceinline__ float sigf(float x) {
    return 1.0f / (1.0f + __expf(-x));
}
__device__ __forceinline__ float tanh_fast(float x) {
    float e = __expf(-2.0f * fabsf(x));
    float t = (1.0f - e) / (1.0f + e);
    return x < 0.0f ? -t : t;
}

// async global->LDS, 16B per lane: dest = wave-uniform base + lane*16
__device__ __forceinline__ void gload_lds16(const u16* g, u16* l) {
    __builtin_amdgcn_global_load_lds(
        (const __attribute__((address_space(1))) void*)g,
        (__attribute__((address_space(3))) void*)l, 16, 0, 0);
}

// ---------------- fp32 -> bf16 cast ----------------
__global__ void cast_bf16_k(const float* __restrict__ in, u16* __restrict__ out, long n4) {
    long i = (long)blockIdx.x * blockDim.x + threadIdx.x;
    long stride = (long)gridDim.x * blockDim.x;
    for (; i < n4; i += stride) {
        float4 v = ((const float4*)in)[i];
        ushort4 o = make_ushort4(f2bf(v.x), f2bf(v.y), f2bf(v.z), f2bf(v.w));
        ((ushort4*)out)[i] = o;
    }
}

// ---------------- xg = x @ W_ih^T + (b_ih+b_hh), out bf16, transposed [t][4096][64] ----------------
// 256x256 tile, 512 thr / 8 waves; wave owns 128x64 (acc[8][4]). BK=32,
// gll width-16 linear-LDS staging. Output now bf16: halves the xgT HBM
// round-trip (write here + fetch in lstm), 512 -> 256 MB.
__global__ __launch_bounds__(512) void xg_gemm_k(
    const u16* __restrict__ A, const u16* __restrict__ Bm,
    const float* __restrict__ bih, const float* __restrict__ bhh,
    u16* __restrict__ out)
{
    __shared__ __align__(16) u16 As[256 * 32];   // linear [256][32]
    __shared__ __align__(16) u16 Bs[256 * 32];

    const int tid  = threadIdx.x;
    const int bg   = blockIdx.y * 256;
    const int btb  = blockIdx.x * 256;
    const int lane = tid & 63;
    const int wid  = tid >> 6;        // 0..7
    const int wr   = wid >> 2;        // 0..1 -> 128 g-rows
    const int wc   = wid & 3;         // 0..3 -> 64 tb-cols
    const int lrow = lane & 15;
    const int lq   = lane >> 4;

    const int grow = wid * 32 + (lane >> 2);   // staging rows 0..15 of chunk
    const int gk   = (lane & 3) * 8;
    const u16* gA = &A [(size_t)(bg  + grow) * 1024 + gk];
    const u16* gB = &Bm[(size_t)(btb + grow) * 1024 + gk];
    u16* lA = &As[wid * 1024];                 // wave-uniform 2KB chunk base
    u16* lB = &Bs[wid * 1024];

    f32x4 acc[8][4];
    #pragma unroll
    for (int i = 0; i < 8; ++i)
        #pragma unroll
        for (int j = 0; j < 4; ++j)
            acc[i][j] = (f32x4){0.f, 0.f, 0.f, 0.f};

    for (int k0 = 0; k0 < 1024; k0 += 32) {
        gload_lds16(gA + k0,             lA);
        gload_lds16(gA + 16 * 1024 + k0, lA + 512);
        gload_lds16(gB + k0,             lB);
        gload_lds16(gB + 16 * 1024 + k0, lB + 512);
        __syncthreads();   // drains vmcnt (gll) for all waves

        bf16x8 af[8], bf[4];
        #pragma unroll
        for (int i = 0; i < 8; ++i)
            af[i] = *(const bf16x8*)&As[(wr * 128 + i * 16 + lrow) * 32 + lq * 8];
        #pragma unroll
        for (int j = 0; j < 4; ++j)
            bf[j] = *(const bf16x8*)&Bs[(wc * 64 + j * 16 + lrow) * 32 + lq * 8];
        #pragma unroll
        for (int mi = 0; mi < 8; ++mi)
            #pragma unroll
            for (int ni = 0; ni < 4; ++ni)
                acc[mi][ni] = __builtin_amdgcn_mfma_f32_16x16x32_bf16(af[mi], bf[ni], acc[mi][ni], 0, 0, 0);
        __syncthreads();
    }

    #pragma unroll
    for (int mi = 0; mi < 8; ++mi) {
        float bsum[4];
        #pragma unroll
        for (int r = 0; r < 4; ++r) {
            int g = bg + wr * 128 + mi * 16 + lq * 4 + r;
            bsum[r] = bih[g] + bhh[g];
        }
        #pragma unroll
        for (int ni = 0; ni < 4; ++ni)
            #pragma unroll
            for (int r = 0; r < 4; ++r) {
                int g  = bg + wr * 128 + mi * 16 + lq * 4 + r;
                int tb = btb + wc * 64 + ni * 16 + lrow;
                int t  = tb >> 6;
                int b  = tb & 63;
                out[((size_t)t * G4 + g) * 64 + b] = f2bf(acc[mi][ni][r] + bsum[r]);
            }
    }
}

// ---------------- persistent LSTM recurrence, fence-free sync (round-5 protocol) ----------------
__global__ __launch_bounds__(256, 1) void lstm_seq_k(
    const u16* __restrict__ Whh,     // bf16 [4096][1024]
    u64* __restrict__ h0b,           // u64 [64][256], parity-0
    u64* __restrict__ h1b,           // parity-1
    float* __restrict__ cT,          // f32 [1024][64]
    const u16* __restrict__ xgT,     // bf16 [tc][4096][64] (chunk-local)
    float* __restrict__ y,           // f32 [T][64][1024]
    unsigned* __restrict__ slots,    // [4][64] u32, zeroed per launch
    int t0, int tc)
{
    __shared__ __align__(16) u16 hs[16 * 1024];   // 32 KB, XOR-swizzled 16B units
    __shared__ float Gs[16][17];

    const int tid  = threadIdx.x;
    const int lane = tid & 63;
    const int w    = tid >> 6;
    const int lq   = lane >> 4;
    const int lr   = lane & 15;
    const int bid  = blockIdx.x;
    const int jwg  = bid >> 2;         // 0..63
    const int quad = bid & 3;
    const int j0   = jwg * 16;
    const int b0   = quad * 16;
    unsigned* qslots = slots + quad * 64;

    // ---- load A fragments once: row m=lr -> (jj=m>>2, gate=m&3) ----
    const int gate = lr & 3;
    const int jja  = lr >> 2;
    const size_t woff = (size_t)(gate * 1024 + j0 + w * 4 + jja) * 1024 + lq * 8;
    bf16x8 af[32];
    #pragma unroll
    for (int kk = 0; kk < 32; ++kk)
        af[kk] = *(const bf16x8*)&Whh[woff + (size_t)kk * 32];

    const int jme = j0 + w * 4 + lq;   // this lane's hidden unit
    const int bme = b0 + lr;           // this lane's batch
    float c = (t0 == 0) ? 0.0f : cT[(size_t)jme * 64 + bme];
    const int swl = lr & 7;

    for (int tt = 0; tt < tc; ++tt) {
        const int gstep = t0 + tt;
        const u64* __restrict__ hin = (gstep & 1) ? h1b : h0b;
        u64* __restrict__ hout      = (gstep & 1) ? h0b : h1b;
        const u16* __restrict__ xg = xgT + (size_t)tt * (G4 * BATCH);

        // prefetch xg (independent of h(t)) before the wait
        float xgv[4];
        #pragma unroll
        for (int g = 0; g < 4; ++g)
            xgv[g] = bf2f(xg[(size_t)(g * 1024 + jme) * 64 + bme]);

        if (tt > 0) {
            const unsigned stamp = (unsigned)tt;
            if (w == 0) {
                while (true) {
                    unsigned v = __hip_atomic_load(&qslots[lane], __ATOMIC_RELAXED, __HIP_MEMORY_SCOPE_AGENT);
                    if (__all((int)(v >= stamp))) break;
                    __builtin_amdgcn_s_sleep(4);
                }
            }
            __syncthreads();
            asm volatile("" ::: "memory");
        }

        // stage h tile [b0..b0+15][1024] -> LDS via bypassing u64 loads,
        // XOR-swizzled 16B units. row stride = 256 u64.
        u64 hv[16];
        #pragma unroll
        for (int s = 0; s < 8; ++s) {
            int g = tid + s * 256;            // 16B-unit index 0..2047
            int row = g >> 7, col = g & 127;
            const u64* p = hin + (size_t)(b0 + row) * 256 + col * 2;
            hv[2 * s]     = __hip_atomic_load(p,     __ATOMIC_RELAXED, __HIP_MEMORY_SCOPE_AGENT);
            hv[2 * s + 1] = __hip_atomic_load(p + 1, __ATOMIC_RELAXED, __HIP_MEMORY_SCOPE_AGENT);
        }
        #pragma unroll
        for (int s = 0; s < 8; ++s) {
            int g = tid + s * 256;
            int row = g >> 7, col = g & 127;
            uint4 q;
            q.x = (u32)hv[2 * s];     q.y = (u32)(hv[2 * s] >> 32);
            q.z = (u32)hv[2 * s + 1]; q.w = (u32)(hv[2 * s + 1] >> 32);
            *(uint4*)&hs[row * 1024 + ((col ^ (row & 7)) * 8)] = q;
        }
        __syncthreads();

        f32x4 acc[4];
        #pragma unroll
        for (int q = 0; q < 4; ++q) acc[q] = (f32x4){0.f, 0.f, 0.f, 0.f};
        #pragma unroll
        for (int kk = 0; kk < 32; ++kk) {
            bf16x8 bf = *(const bf16x8*)&hs[lr * 1024 + (((lq + 4 * kk) ^ swl) * 8)];
            acc[kk & 3] = __builtin_amdgcn_mfma_f32_16x16x32_bf16(af[kk], bf, acc[kk & 3], 0, 0, 0);
        }
        f32x4 g4 = (acc[0] + acc[1]) + (acc[2] + acc[3]);

        // lane-local gates: reg r = gate r for (jme, bme)
        float cn = sigf(g4[1] + xgv[1]) * c + sigf(g4[0] + xgv[0]) * tanh_fast(g4[2] + xgv[2]);
        float hn = sigf(g4[3] + xgv[3]) * tanh_fast(cn);
        c = cn;

        // pack this wave's 4 j-values per b-row into one u64, store write-through
        float h1 = __shfl(hn, lr + 16);
        float h2 = __shfl(hn, lr + 32);
        float h3 = __shfl(hn, lr + 48);
        if (lq == 0) {
            u64 pv = (u64)f2bf(hn) | ((u64)f2bf(h1) << 16) |
                     ((u64)f2bf(h2) << 32) | ((u64)f2bf(h3) << 48);
            __hip_atomic_store(hout + (size_t)(b0 + lr) * 256 + (j0 >> 2) + w, pv,
                               __ATOMIC_RELAXED, __HIP_MEMORY_SCOPE_AGENT);
        }
        Gs[w * 4 + lq][lr] = hn;

        asm volatile("s_waitcnt vmcnt(0)" ::: "memory");   // h stores acked at coherence point
        __syncthreads();                                    // whole WG drained + Gs ready
        if (tid == 0)
            __hip_atomic_store(&qslots[jwg], (unsigned)(tt + 1),
                               __ATOMIC_RELAXED, __HIP_MEMORY_SCOPE_AGENT);

        // y stores after the signal (off the critical path)
        int bb = tid >> 4, jj = tid & 15;
        float* yt = y + (size_t)gstep * (BATCH * HID_F);
        yt[(size_t)(b0 + bb) * 1024 + j0 + jj] = Gs[jj][bb];
    }
    cT[(size_t)jme * 64 + bme] = c;
}

extern "C" void kernel_launch(void* const* d_in, const int* in_sizes, int n_in,
                              void* d_out, int out_size, void* d_ws, size_t ws_size,
                              hipStream_t stream) {
    const float* x    = (const float*)d_in[0];
    const float* Wih  = (const float*)d_in[1];
    const float* Whh  = (const float*)d_in[2];
    const float* bih  = (const float*)d_in[3];
    const float* bhh  = (const float*)d_in[4];
    float* y = (float*)d_out;

    char* ws = (char*)d_ws;
    size_t off = 0;
    auto alloc = [&](size_t bytes) { size_t p = off; off += (bytes + 255) & ~(size_t)255; return p; };

    unsigned* slots = (unsigned*)(ws + alloc(4 * 64 * 4));   // [4][64]
    u16* xb    = (u16*)(ws + alloc((size_t)T_SEQ * BATCH * IN_F * 2));  // 64 MB
    u16* wihb  = (u16*)(ws + alloc((size_t)G4 * IN_F * 2));             // 8 MB
    u16* whhb  = (u16*)(ws + alloc((size_t)G4 * HID_F * 2));            // 8 MB
    u64* hbuf0 = (u64*)(ws + alloc((size_t)BATCH * 256 * 8));           // 128 KB
    u64* hbuf1 = (u64*)(ws + alloc((size_t)BATCH * 256 * 8));           // 128 KB
    float* cT  = (float*)(ws + alloc((size_t)HID_F * BATCH * 4));

    size_t slot_bytes = (size_t)G4 * BATCH * 2;   // 0.5 MB per timestep (bf16)
    size_t remain = ws_size > off ? ws_size - off : 0;
    long ringT = (long)(remain / slot_bytes);
    if (ringT > 256) ringT = 256;                  // 2 chunks: xgT 128MB = L3-resident,
    ringT &= ~3L;                                  // and xg duration becomes measurable
    if (ringT < 4) ringT = 4;                      // via inter-lstm timestamp gaps
    u16* xgT = (u16*)(ws + alloc((size_t)ringT * slot_bytes));

    cast_bf16_k<<<2048, 256, 0, stream>>>(x,   xb,   (long)T_SEQ * BATCH * IN_F / 4);
    cast_bf16_k<<<512,  256, 0, stream>>>(Wih, wihb, (long)G4 * IN_F / 4);
    cast_bf16_k<<<512,  256, 0, stream>>>(Whh, whhb, (long)G4 * HID_F / 4);

    hipMemsetAsync(hbuf0, 0, (size_t)BATCH * 256 * 8, stream);   // h(0) = 0

    for (long t0 = 0; t0 < T_SEQ; t0 += ringT) {
        long tc = T_SEQ - t0 < ringT ? T_SEQ - t0 : ringT;
        dim3 ggrid((unsigned)(tc * BATCH / 256), G4 / 256);
        xg_gemm_k<<<ggrid, 512, 0, stream>>>(wihb, xb + (size_t)t0 * BATCH * IN_F, bih, bhh, xgT);
        hipMemsetAsync(slots, 0, 4 * 64 * 4, stream);
        lstm_seq_k<<<256, 256, 0, stream>>>(whhb, hbuf0, hbuf1, cT, xgT, y, slots, (int)t0, (int)tc);
    }
}

// Round 18
// 2760.344 us; speedup vs baseline: 1.0035x; 1.0035x over previous
//
#include <hip/hip_runtime.h>

#define T_SEQ 512
#define BATCH 64
#define IN_F  1024
#define HID_F 1024
#define G4    4096

typedef __bf16 bf16x8 __attribute__((ext_vector_type(8)));
typedef float  f32x4  __attribute__((ext_vector_type(4)));
typedef unsigned short u16;
typedef unsigned int   u32;
typedef unsigned long long u64;

__device__ __forceinline__ u16 f2bf(float x) {
    u32 u = __builtin_bit_cast(u32, x);
    u = (u + 0x7FFFu + ((u >> 16) & 1u)) >> 16;   // RTNE
    return (u16)u;
}
__device__ __forceinline__ float bf2f(u16 v) {
    return __builtin_bit_cast(float, (u32)v << 16);
}

__device__ __forceinline__ float sigf(float x) {
    return 1.0f / (1.0f + __expf(-x));
}
__device__ __forceinline__ float tanh_fast(float x) {
    float e = __expf(-2.0f * fabsf(x));
    float t = (1.0f - e) / (1.0f + e);
    return x < 0.0f ? -t : t;
}

// async global->LDS, 16B per lane: dest = wave-uniform base + lane*16
__device__ __forceinline__ void gload_lds16(const u16* g, u16* l) {
    __builtin_amdgcn_global_load_lds(
        (const __attribute__((address_space(1))) void*)g,
        (__attribute__((address_space(3))) void*)l, 16, 0, 0);
}

// ---------------- fp32 -> bf16 cast ----------------
__global__ void cast_bf16_k(const float* __restrict__ in, u16* __restrict__ out, long n4) {
    long i = (long)blockIdx.x * blockDim.x + threadIdx.x;
    long stride = (long)gridDim.x * blockDim.x;
    for (; i < n4; i += stride) {
        float4 v = ((const float4*)in)[i];
        ushort4 o = make_ushort4(f2bf(v.x), f2bf(v.y), f2bf(v.z), f2bf(v.w));
        ((ushort4*)out)[i] = o;
    }
}

// ---------------- xg = x @ W_ih^T + (b_ih+b_hh), out bf16, transposed [t][4096][64] ----------------
// 256x256 tile, 512 thr / 8 waves; wave owns 128x64 (acc[8][4]). BK=32,
// gll width-16 linear-LDS staging. Output now bf16: halves the xgT HBM
// round-trip (write here + fetch in lstm), 512 -> 256 MB.
__global__ __launch_bounds__(512) void xg_gemm_k(
    const u16* __restrict__ A, const u16* __restrict__ Bm,
    const float* __restrict__ bih, const float* __restrict__ bhh,
    u16* __restrict__ out)
{
    __shared__ __align__(16) u16 As[256 * 32];   // linear [256][32]
    __shared__ __align__(16) u16 Bs[256 * 32];

    const int tid  = threadIdx.x;
    const int bg   = blockIdx.y * 256;
    const int btb  = blockIdx.x * 256;
    const int lane = tid & 63;
    const int wid  = tid >> 6;        // 0..7
    const int wr   = wid >> 2;        // 0..1 -> 128 g-rows
    const int wc   = wid & 3;         // 0..3 -> 64 tb-cols
    const int lrow = lane & 15;
    const int lq   = lane >> 4;

    const int grow = wid * 32 + (lane >> 2);   // staging rows 0..15 of chunk
    const int gk   = (lane & 3) * 8;
    const u16* gA = &A [(size_t)(bg  + grow) * 1024 + gk];
    const u16* gB = &Bm[(size_t)(btb + grow) * 1024 + gk];
    u16* lA = &As[wid * 1024];                 // wave-uniform 2KB chunk base
    u16* lB = &Bs[wid * 1024];

    f32x4 acc[8][4];
    #pragma unroll
    for (int i = 0; i < 8; ++i)
        #pragma unroll
        for (int j = 0; j < 4; ++j)
            acc[i][j] = (f32x4){0.f, 0.f, 0.f, 0.f};

    for (int k0 = 0; k0 < 1024; k0 += 32) {
        gload_lds16(gA + k0,             lA);
        gload_lds16(gA + 16 * 1024 + k0, lA + 512);
        gload_lds16(gB + k0,             lB);
        gload_lds16(gB + 16 * 1024 + k0, lB + 512);
        __syncthreads();   // drains vmcnt (gll) for all waves

        bf16x8 af[8], bf[4];
        #pragma unroll
        for (int i = 0; i < 8; ++i)
            af[i] = *(const bf16x8*)&As[(wr * 128 + i * 16 + lrow) * 32 + lq * 8];
        #pragma unroll
        for (int j = 0; j < 4; ++j)
            bf[j] = *(const bf16x8*)&Bs[(wc * 64 + j * 16 + lrow) * 32 + lq * 8];
        #pragma unroll
        for (int mi = 0; mi < 8; ++mi)
            #pragma unroll
            for (int ni = 0; ni < 4; ++ni)
                acc[mi][ni] = __builtin_amdgcn_mfma_f32_16x16x32_bf16(af[mi], bf[ni], acc[mi][ni], 0, 0, 0);
        __syncthreads();
    }

    #pragma unroll
    for (int mi = 0; mi < 8; ++mi) {
        float bsum[4];
        #pragma unroll
        for (int r = 0; r < 4; ++r) {
            int g = bg + wr * 128 + mi * 16 + lq * 4 + r;
            bsum[r] = bih[g] + bhh[g];
        }
        #pragma unroll
        for (int ni = 0; ni < 4; ++ni)
            #pragma unroll
            for (int r = 0; r < 4; ++r) {
                int g  = bg + wr * 128 + mi * 16 + lq * 4 + r;
                int tb = btb + wc * 64 + ni * 16 + lrow;
                int t  = tb >> 6;
                int b  = tb & 63;
                out[((size_t)t * G4 + g) * 64 + b] = f2bf(acc[mi][ni][r] + bsum[r]);
            }
    }
}

// ---------------- persistent LSTM recurrence, fence-free sync (round-5 protocol) ----------------
__global__ __launch_bounds__(256, 1) void lstm_seq_k(
    const u16* __restrict__ Whh,     // bf16 [4096][1024]
    u64* __restrict__ h0b,           // u64 [64][256], parity-0
    u64* __restrict__ h1b,           // parity-1
    float* __restrict__ cT,          // f32 [1024][64]
    const u16* __restrict__ xgT,     // bf16 [tc][4096][64] (chunk-local)
    float* __restrict__ y,           // f32 [T][64][1024]
    unsigned* __restrict__ slots,    // [4][64] u32, zeroed per launch
    int t0, int tc)
{
    __shared__ __align__(16) u16 hs[16 * 1024];   // 32 KB, XOR-swizzled 16B units
    __shared__ float Gs[16][17];

    const int tid  = threadIdx.x;
    const int lane = tid & 63;
    const int w    = tid >> 6;
    const int lq   = lane >> 4;
    const int lr   = lane & 15;
    const int bid  = blockIdx.x;
    const int jwg  = bid >> 2;         // 0..63
    const int quad = bid & 3;
    const int j0   = jwg * 16;
    const int b0   = quad * 16;
    unsigned* qslots = slots + quad * 64;

    // ---- load A fragments once: row m=lr -> (jj=m>>2, gate=m&3) ----
    const int gate = lr & 3;
    const int jja  = lr >> 2;
    const size_t woff = (size_t)(gate * 1024 + j0 + w * 4 + jja) * 1024 + lq * 8;
    bf16x8 af[32];
    #pragma unroll
    for (int kk = 0; kk < 32; ++kk)
        af[kk] = *(const bf16x8*)&Whh[woff + (size_t)kk * 32];

    const int jme = j0 + w * 4 + lq;   // this lane's hidden unit
    const int bme = b0 + lr;           // this lane's batch
    float c = (t0 == 0) ? 0.0f : cT[(size_t)jme * 64 + bme];
    const int swl = lr & 7;

    for (int tt = 0; tt < tc; ++tt) {
        const int gstep = t0 + tt;
        const u64* __restrict__ hin = (gstep & 1) ? h1b : h0b;
        u64* __restrict__ hout      = (gstep & 1) ? h0b : h1b;
        const u16* __restrict__ xg = xgT + (size_t)tt * (G4 * BATCH);

        // prefetch xg (independent of h(t)) before the wait
        float xgv[4];
        #pragma unroll
        for (int g = 0; g < 4; ++g)
            xgv[g] = bf2f(xg[(size_t)(g * 1024 + jme) * 64 + bme]);

        if (tt > 0) {
            const unsigned stamp = (unsigned)tt;
            if (w == 0) {
                while (true) {
                    unsigned v = __hip_atomic_load(&qslots[lane], __ATOMIC_RELAXED, __HIP_MEMORY_SCOPE_AGENT);
                    if (__all((int)(v >= stamp))) break;
                    __builtin_amdgcn_s_sleep(4);
                }
            }
            __syncthreads();
            asm volatile("" ::: "memory");
        }

        // stage h tile [b0..b0+15][1024] -> LDS via bypassing u64 loads,
        // XOR-swizzled 16B units. row stride = 256 u64.
        u64 hv[16];
        #pragma unroll
        for (int s = 0; s < 8; ++s) {
            int g = tid + s * 256;            // 16B-unit index 0..2047
            int row = g >> 7, col = g & 127;
            const u64* p = hin + (size_t)(b0 + row) * 256 + col * 2;
            hv[2 * s]     = __hip_atomic_load(p,     __ATOMIC_RELAXED, __HIP_MEMORY_SCOPE_AGENT);
            hv[2 * s + 1] = __hip_atomic_load(p + 1, __ATOMIC_RELAXED, __HIP_MEMORY_SCOPE_AGENT);
        }
        #pragma unroll
        for (int s = 0; s < 8; ++s) {
            int g = tid + s * 256;
            int row = g >> 7, col = g & 127;
            uint4 q;
            q.x = (u32)hv[2 * s];     q.y = (u32)(hv[2 * s] >> 32);
            q.z = (u32)hv[2 * s + 1]; q.w = (u32)(hv[2 * s + 1] >> 32);
            *(uint4*)&hs[row * 1024 + ((col ^ (row & 7)) * 8)] = q;
        }
        __syncthreads();

        f32x4 acc[4];
        #pragma unroll
        for (int q = 0; q < 4; ++q) acc[q] = (f32x4){0.f, 0.f, 0.f, 0.f};
        #pragma unroll
        for (int kk = 0; kk < 32; ++kk) {
            bf16x8 bf = *(const bf16x8*)&hs[lr * 1024 + (((lq + 4 * kk) ^ swl) * 8)];
            acc[kk & 3] = __builtin_amdgcn_mfma_f32_16x16x32_bf16(af[kk], bf, acc[kk & 3], 0, 0, 0);
        }
        f32x4 g4 = (acc[0] + acc[1]) + (acc[2] + acc[3]);

        // lane-local gates: reg r = gate r for (jme, bme)
        float cn = sigf(g4[1] + xgv[1]) * c + sigf(g4[0] + xgv[0]) * tanh_fast(g4[2] + xgv[2]);
        float hn = sigf(g4[3] + xgv[3]) * tanh_fast(cn);
        c = cn;

        // pack this wave's 4 j-values per b-row into one u64, store write-through
        float h1 = __shfl(hn, lr + 16);
        float h2 = __shfl(hn, lr + 32);
        float h3 = __shfl(hn, lr + 48);
        if (lq == 0) {
            u64 pv = (u64)f2bf(hn) | ((u64)f2bf(h1) << 16) |
                     ((u64)f2bf(h2) << 32) | ((u64)f2bf(h3) << 48);
            __hip_atomic_store(hout + (size_t)(b0 + lr) * 256 + (j0 >> 2) + w, pv,
                               __ATOMIC_RELAXED, __HIP_MEMORY_SCOPE_AGENT);
        }
        Gs[w * 4 + lq][lr] = hn;

        asm volatile("s_waitcnt vmcnt(0)" ::: "memory");   // h stores acked at coherence point
        __syncthreads();                                    // whole WG drained + Gs ready
        if (tid == 0)
            __hip_atomic_store(&qslots[jwg], (unsigned)(tt + 1),
                               __ATOMIC_RELAXED, __HIP_MEMORY_SCOPE_AGENT);

        // y stores after the signal (off the critical path)
        int bb = tid >> 4, jj = tid & 15;
        float* yt = y + (size_t)gstep * (BATCH * HID_F);
        yt[(size_t)(b0 + bb) * 1024 + j0 + jj] = Gs[jj][bb];
    }
    cT[(size_t)jme * 64 + bme] = c;
}

extern "C" void kernel_launch(void* const* d_in, const int* in_sizes, int n_in,
                              void* d_out, int out_size, void* d_ws, size_t ws_size,
                              hipStream_t stream) {
    const float* x    = (const float*)d_in[0];
    const float* Wih  = (const float*)d_in[1];
    const float* Whh  = (const float*)d_in[2];
    const float* bih  = (const float*)d_in[3];
    const float* bhh  = (const float*)d_in[4];
    float* y = (float*)d_out;

    char* ws = (char*)d_ws;
    size_t off = 0;
    auto alloc = [&](size_t bytes) { size_t p = off; off += (bytes + 255) & ~(size_t)255; return p; };

    unsigned* slots = (unsigned*)(ws + alloc(4 * 64 * 4));   // [4][64]
    u16* xb    = (u16*)(ws + alloc((size_t)T_SEQ * BATCH * IN_F * 2));  // 64 MB
    u16* wihb  = (u16*)(ws + alloc((size_t)G4 * IN_F * 2));             // 8 MB
    u16* whhb  = (u16*)(ws + alloc((size_t)G4 * HID_F * 2));            // 8 MB
    u64* hbuf0 = (u64*)(ws + alloc((size_t)BATCH * 256 * 8));           // 128 KB
    u64* hbuf1 = (u64*)(ws + alloc((size_t)BATCH * 256 * 8));           // 128 KB
    float* cT  = (float*)(ws + alloc((size_t)HID_F * BATCH * 4));

    size_t slot_bytes = (size_t)G4 * BATCH * 2;   // 0.5 MB per timestep (bf16)
    size_t remain = ws_size > off ? ws_size - off : 0;
    long ringT = (long)(remain / slot_bytes);
    if (ringT > 256) ringT = 256;                  // 2 chunks: xgT 128MB = L3-resident,
    ringT &= ~3L;                                  // and xg duration becomes measurable
    if (ringT < 4) ringT = 4;                      // via inter-lstm timestamp gaps
    u16* xgT = (u16*)(ws + alloc((size_t)ringT * slot_bytes));

    cast_bf16_k<<<2048, 256, 0, stream>>>(x,   xb,   (long)T_SEQ * BATCH * IN_F / 4);
    cast_bf16_k<<<512,  256, 0, stream>>>(Wih, wihb, (long)G4 * IN_F / 4);
    cast_bf16_k<<<512,  256, 0, stream>>>(Whh, whhb, (long)G4 * HID_F / 4);

    hipMemsetAsync(hbuf0, 0, (size_t)BATCH * 256 * 8, stream);   // h(0) = 0

    for (long t0 = 0; t0 < T_SEQ; t0 += ringT) {
        long tc = T_SEQ - t0 < ringT ? T_SEQ - t0 : ringT;
        dim3 ggrid((unsigned)(tc * BATCH / 256), G4 / 256);
        xg_gemm_k<<<ggrid, 512, 0, stream>>>(wihb, xb + (size_t)t0 * BATCH * IN_F, bih, bhh, xgT);
        hipMemsetAsync(slots, 0, 4 * 64 * 4, stream);
        lstm_seq_k<<<256, 256, 0, stream>>>(whhb, hbuf0, hbuf1, cT, xgT, y, slots, (int)t0, (int)tc);
    }
}

// Round 19
// 2656.432 us; speedup vs baseline: 1.0427x; 1.0391x over previous
//
#include <hip/hip_runtime.h>

#define T_SEQ 512
#define BATCH 64
#define IN_F  1024
#define HID_F 1024
#define G4    4096

typedef __bf16 bf16x8 __attribute__((ext_vector_type(8)));
typedef float  f32x4  __attribute__((ext_vector_type(4)));
typedef unsigned short u16;
typedef unsigned int   u32;
typedef unsigned long long u64;

__device__ __forceinline__ u16 f2bf(float x) {
    u32 u = __builtin_bit_cast(u32, x);
    u = (u + 0x7FFFu + ((u >> 16) & 1u)) >> 16;   // RTNE
    return (u16)u;
}
__device__ __forceinline__ float bf2f(u16 v) {
    return __builtin_bit_cast(float, (u32)v << 16);
}

__device__ __forceinline__ float sigf(float x) {
    return 1.0f / (1.0f + __expf(-x));
}
__device__ __forceinline__ float tanh_fast(float x) {
    float e = __expf(-2.0f * fabsf(x));
    float t = (1.0f - e) / (1.0f + e);
    return x < 0.0f ? -t : t;
}

// async global->LDS, 16B per lane: dest = wave-uniform base + lane*16
__device__ __forceinline__ void gload_lds16(const u16* g, u16* l) {
    __builtin_amdgcn_global_load_lds(
        (const __attribute__((address_space(1))) void*)g,
        (__attribute__((address_space(3))) void*)l, 16, 0, 0);
}

// ---------------- fp32 -> bf16 cast ----------------
__global__ void cast_bf16_k(const float* __restrict__ in, u16* __restrict__ out, long n4) {
    long i = (long)blockIdx.x * blockDim.x + threadIdx.x;
    long stride = (long)gridDim.x * blockDim.x;
    for (; i < n4; i += stride) {
        float4 v = ((const float4*)in)[i];
        ushort4 o = make_ushort4(f2bf(v.x), f2bf(v.y), f2bf(v.z), f2bf(v.w));
        ((ushort4*)out)[i] = o;
    }
}

// ---------------- xg = x @ W_ih^T + bias, out bf16 GATE-INTERLEAVED [t][j][b][gate] ----------------
// 256x256 tile, 512 thr / 8 waves; wave owns 128x64 (acc[8][4]). BK=32, gll
// width-16 linear-LDS staging with PERMUTED A-row source: LDS row m holds
// W row (m&3)*1024 + jbase + (m>>2), so MFMA D's 4 consecutive rows (lq*4+r)
// are the 4 gates of one j -> epilogue packs them into ONE u64 store
// (16 lanes = 128B contiguous), and lstm reads them as ONE u64 load.
__global__ __launch_bounds__(512) void xg_gemm_k(
    const u16* __restrict__ A, const u16* __restrict__ Bm,
    const float* __restrict__ bih, const float* __restrict__ bhh,
    u16* __restrict__ out)
{
    __shared__ __align__(16) u16 As[256 * 32];   // linear [256][32]
    __shared__ __align__(16) u16 Bs[256 * 32];

    const int tid   = threadIdx.x;
    const int jbase = blockIdx.y * 64;    // 64 j's per block (x4 gates = 256 rows)
    const int btb   = blockIdx.x * 256;
    const int lane  = tid & 63;
    const int wid   = tid >> 6;        // 0..7
    const int wr    = wid >> 2;        // 0..1 -> 128 tile-rows
    const int wc    = wid & 3;         // 0..3 -> 64 tb-cols
    const int lrow  = lane & 15;
    const int lq    = lane >> 4;

    // staging: LDS row m = wid*32 + (lane>>2); W row = (m&3)*1024 + jbase + (m>>2)
    const int m0   = wid * 32 + (lane >> 2);
    const int gk   = (lane & 3) * 8;
    const u16* gA = &A [(size_t)((m0 & 3) * 1024 + jbase + (m0 >> 2)) * 1024 + gk];
    const u16* gB = &Bm[(size_t)(btb + m0) * 1024 + gk];
    u16* lA = &As[wid * 1024];                 // wave-uniform 2KB chunk base
    u16* lB = &Bs[wid * 1024];

    f32x4 acc[8][4];
    #pragma unroll
    for (int i = 0; i < 8; ++i)
        #pragma unroll
        for (int j = 0; j < 4; ++j)
            acc[i][j] = (f32x4){0.f, 0.f, 0.f, 0.f};

    for (int k0 = 0; k0 < 1024; k0 += 32) {
        // rows m0..m0+15 at source row +0; rows m0+16..31 at source row +4
        gload_lds16(gA + k0,            lA);
        gload_lds16(gA + 4 * 1024 + k0, lA + 512);
        gload_lds16(gB + k0,            lB);
        gload_lds16(gB + 16 * 1024 + k0, lB + 512);
        __syncthreads();   // drains vmcnt (gll) for all waves

        bf16x8 af[8], bf[4];
        #pragma unroll
        for (int i = 0; i < 8; ++i)
            af[i] = *(const bf16x8*)&As[(wr * 128 + i * 16 + lrow) * 32 + lq * 8];
        #pragma unroll
        for (int j = 0; j < 4; ++j)
            bf[j] = *(const bf16x8*)&Bs[(wc * 64 + j * 16 + lrow) * 32 + lq * 8];
        #pragma unroll
        for (int mi = 0; mi < 8; ++mi)
            #pragma unroll
            for (int ni = 0; ni < 4; ++ni)
                acc[mi][ni] = __builtin_amdgcn_mfma_f32_16x16x32_bf16(af[mi], bf[ni], acc[mi][ni], 0, 0, 0);
        __syncthreads();
    }

    // D row (lq*4+r) of tile-row block m: j = jbase + (m>>2), gate = r
    #pragma unroll
    for (int mi = 0; mi < 8; ++mi) {
        const int jo = jbase + wr * 32 + mi * 4 + lq;   // this lane's j
        float bsum[4];
        #pragma unroll
        for (int r = 0; r < 4; ++r)
            bsum[r] = bih[r * 1024 + jo] + bhh[r * 1024 + jo];
        #pragma unroll
        for (int ni = 0; ni < 4; ++ni) {
            int tb = btb + wc * 64 + ni * 16 + lrow;
            int t  = tb >> 6;
            int b  = tb & 63;
            u64 pv = (u64)f2bf(acc[mi][ni][0] + bsum[0])
                   | ((u64)f2bf(acc[mi][ni][1] + bsum[1]) << 16)
                   | ((u64)f2bf(acc[mi][ni][2] + bsum[2]) << 32)
                   | ((u64)f2bf(acc[mi][ni][3] + bsum[3]) << 48);
            *(u64*)&out[(((size_t)t * 1024 + jo) * 64 + b) * 4] = pv;
        }
    }
}

// ---------------- persistent LSTM recurrence, fence-free sync (round-5 protocol) ----------------
__global__ __launch_bounds__(256, 1) void lstm_seq_k(
    const u16* __restrict__ Whh,     // bf16 [4096][1024]
    u64* __restrict__ h0b,           // u64 [64][256], parity-0
    u64* __restrict__ h1b,           // parity-1
    float* __restrict__ cT,          // f32 [1024][64]
    const u16* __restrict__ xgT,     // bf16 [tc][1024 j][64 b][4 gates]
    float* __restrict__ y,           // f32 [T][64][1024]
    unsigned* __restrict__ slots,    // [4][64] u32, zeroed per launch
    int t0, int tc)
{
    __shared__ __align__(16) u16 hs[16 * 1024];   // 32 KB, XOR-swizzled 16B units
    __shared__ float Gs[16][17];

    const int tid  = threadIdx.x;
    const int lane = tid & 63;
    const int w    = tid >> 6;
    const int lq   = lane >> 4;
    const int lr   = lane & 15;
    const int bid  = blockIdx.x;
    const int jwg  = bid >> 2;         // 0..63
    const int quad = bid & 3;
    const int j0   = jwg * 16;
    const int b0   = quad * 16;
    unsigned* qslots = slots + quad * 64;

    // ---- load A fragments once: row m=lr -> (jj=m>>2, gate=m&3) ----
    const int gate = lr & 3;
    const int jja  = lr >> 2;
    const size_t woff = (size_t)(gate * 1024 + j0 + w * 4 + jja) * 1024 + lq * 8;
    bf16x8 af[32];
    #pragma unroll
    for (int kk = 0; kk < 32; ++kk)
        af[kk] = *(const bf16x8*)&Whh[woff + (size_t)kk * 32];

    const int jme = j0 + w * 4 + lq;   // this lane's hidden unit
    const int bme = b0 + lr;           // this lane's batch
    float c = (t0 == 0) ? 0.0f : cT[(size_t)jme * 64 + bme];
    const int swl = lr & 7;

    for (int tt = 0; tt < tc; ++tt) {
        const int gstep = t0 + tt;
        const u64* __restrict__ hin = (gstep & 1) ? h1b : h0b;
        u64* __restrict__ hout      = (gstep & 1) ? h0b : h1b;
        const u16* __restrict__ xg = xgT + (size_t)tt * (G4 * BATCH);

        // prefetch xg: ONE aligned 8B load = all 4 gates of (jme, bme)
        u64 xgp = *(const u64*)&xg[(((size_t)jme * 64) + bme) * 4];
        float xgv[4];
        #pragma unroll
        for (int g = 0; g < 4; ++g)
            xgv[g] = bf2f((u16)(xgp >> (16 * g)));

        if (tt > 0) {
            const unsigned stamp = (unsigned)tt;
            if (w == 0) {
                while (true) {
                    unsigned v = __hip_atomic_load(&qslots[lane], __ATOMIC_RELAXED, __HIP_MEMORY_SCOPE_AGENT);
                    if (__all((int)(v >= stamp))) break;
                    __builtin_amdgcn_s_sleep(4);
                }
            }
            __syncthreads();
            asm volatile("" ::: "memory");
        }

        // stage h tile [b0..b0+15][1024] -> LDS via bypassing u64 loads,
        // XOR-swizzled 16B units. row stride = 256 u64.
        u64 hv[16];
        #pragma unroll
        for (int s = 0; s < 8; ++s) {
            int g = tid + s * 256;            // 16B-unit index 0..2047
            int row = g >> 7, col = g & 127;
            const u64* p = hin + (size_t)(b0 + row) * 256 + col * 2;
            hv[2 * s]     = __hip_atomic_load(p,     __ATOMIC_RELAXED, __HIP_MEMORY_SCOPE_AGENT);
            hv[2 * s + 1] = __hip_atomic_load(p + 1, __ATOMIC_RELAXED, __HIP_MEMORY_SCOPE_AGENT);
        }
        #pragma unroll
        for (int s = 0; s < 8; ++s) {
            int g = tid + s * 256;
            int row = g >> 7, col = g & 127;
            uint4 q;
            q.x = (u32)hv[2 * s];     q.y = (u32)(hv[2 * s] >> 32);
            q.z = (u32)hv[2 * s + 1]; q.w = (u32)(hv[2 * s + 1] >> 32);
            *(uint4*)&hs[row * 1024 + ((col ^ (row & 7)) * 8)] = q;
        }
        __syncthreads();

        f32x4 acc[4];
        #pragma unroll
        for (int q = 0; q < 4; ++q) acc[q] = (f32x4){0.f, 0.f, 0.f, 0.f};
        #pragma unroll
        for (int kk = 0; kk < 32; ++kk) {
            bf16x8 bf = *(const bf16x8*)&hs[lr * 1024 + (((lq + 4 * kk) ^ swl) * 8)];
            acc[kk & 3] = __builtin_amdgcn_mfma_f32_16x16x32_bf16(af[kk], bf, acc[kk & 3], 0, 0, 0);
        }
        f32x4 g4 = (acc[0] + acc[1]) + (acc[2] + acc[3]);

        // lane-local gates: reg r = gate r for (jme, bme)
        float cn = sigf(g4[1] + xgv[1]) * c + sigf(g4[0] + xgv[0]) * tanh_fast(g4[2] + xgv[2]);
        float hn = sigf(g4[3] + xgv[3]) * tanh_fast(cn);
        c = cn;

        // pack this wave's 4 j-values per b-row into one u64, store write-through
        float h1 = __shfl(hn, lr + 16);
        float h2 = __shfl(hn, lr + 32);
        float h3 = __shfl(hn, lr + 48);
        if (lq == 0) {
            u64 pv = (u64)f2bf(hn) | ((u64)f2bf(h1) << 16) |
                     ((u64)f2bf(h2) << 32) | ((u64)f2bf(h3) << 48);
            __hip_atomic_store(hout + (size_t)(b0 + lr) * 256 + (j0 >> 2) + w, pv,
                               __ATOMIC_RELAXED, __HIP_MEMORY_SCOPE_AGENT);
        }
        Gs[w * 4 + lq][lr] = hn;

        asm volatile("s_waitcnt vmcnt(0)" ::: "memory");   // h stores acked at coherence point
        __syncthreads();                                    // whole WG drained + Gs ready
        if (tid == 0)
            __hip_atomic_store(&qslots[jwg], (unsigned)(tt + 1),
                               __ATOMIC_RELAXED, __HIP_MEMORY_SCOPE_AGENT);

        // y stores after the signal (off the critical path)
        int bb = tid >> 4, jj = tid & 15;
        float* yt = y + (size_t)gstep * (BATCH * HID_F);
        yt[(size_t)(b0 + bb) * 1024 + j0 + jj] = Gs[jj][bb];
    }
    cT[(size_t)jme * 64 + bme] = c;
}

extern "C" void kernel_launch(void* const* d_in, const int* in_sizes, int n_in,
                              void* d_out, int out_size, void* d_ws, size_t ws_size,
                              hipStream_t stream) {
    const float* x    = (const float*)d_in[0];
    const float* Wih  = (const float*)d_in[1];
    const float* Whh  = (const float*)d_in[2];
    const float* bih  = (const float*)d_in[3];
    const float* bhh  = (const float*)d_in[4];
    float* y = (float*)d_out;

    char* ws = (char*)d_ws;
    size_t off = 0;
    auto alloc = [&](size_t bytes) { size_t p = off; off += (bytes + 255) & ~(size_t)255; return p; };

    unsigned* slots = (unsigned*)(ws + alloc(4 * 64 * 4));   // [4][64]
    u16* xb    = (u16*)(ws + alloc((size_t)T_SEQ * BATCH * IN_F * 2));  // 64 MB
    u16* wihb  = (u16*)(ws + alloc((size_t)G4 * IN_F * 2));             // 8 MB
    u16* whhb  = (u16*)(ws + alloc((size_t)G4 * HID_F * 2));            // 8 MB
    u64* hbuf0 = (u64*)(ws + alloc((size_t)BATCH * 256 * 8));           // 128 KB
    u64* hbuf1 = (u64*)(ws + alloc((size_t)BATCH * 256 * 8));           // 128 KB
    float* cT  = (float*)(ws + alloc((size_t)HID_F * BATCH * 4));

    size_t slot_bytes = (size_t)G4 * BATCH * 2;   // 0.5 MB per timestep (bf16)
    size_t remain = ws_size > off ? ws_size - off : 0;
    long ringT = (long)(remain / slot_bytes);
    if (ringT > 256) ringT = 256;                  // 2 chunks (L3-resident xgT)
    ringT &= ~3L;
    if (ringT < 4) ringT = 4;
    u16* xgT = (u16*)(ws + alloc((size_t)ringT * slot_bytes));

    cast_bf16_k<<<2048, 256, 0, stream>>>(x,   xb,   (long)T_SEQ * BATCH * IN_F / 4);
    cast_bf16_k<<<512,  256, 0, stream>>>(Wih, wihb, (long)G4 * IN_F / 4);
    cast_bf16_k<<<512,  256, 0, stream>>>(Whh, whhb, (long)G4 * HID_F / 4);

    hipMemsetAsync(hbuf0, 0, (size_t)BATCH * 256 * 8, stream);   // h(0) = 0

    for (long t0 = 0; t0 < T_SEQ; t0 += ringT) {
        long tc = T_SEQ - t0 < ringT ? T_SEQ - t0 : ringT;
        dim3 ggrid((unsigned)(tc * BATCH / 256), G4 / 256);
        xg_gemm_k<<<ggrid, 512, 0, stream>>>(wihb, xb + (size_t)t0 * BATCH * IN_F, bih, bhh, xgT);
        hipMemsetAsync(slots, 0, 4 * 64 * 4, stream);
        lstm_seq_k<<<256, 256, 0, stream>>>(whhb, hbuf0, hbuf1, cT, xgT, y, slots, (int)t0, (int)tc);
    }
}